// Round 6
// baseline (814.454 us; speedup 1.0000x reference)
//
#include <hip/hip_runtime.h>
#include <hip/hip_bf16.h>

// Sizes (fixed by the problem)
#define C2   512
#define Tn   512
#define Bn   32
#define En   256
#define Mn   8
#define Nn   5
#define MN   40
#define Rn   64
#define KBIG 1024
#define SCALE_INV (1.0f/22.62741699796952f)   // 1/sqrt(512)

typedef __attribute__((ext_vector_type(8))) __bf16 bf16x8;
typedef __attribute__((ext_vector_type(4))) float f32x4;

// ---------- helpers ----------
__device__ __forceinline__ unsigned short f2bf(float f) {
  union { float f; unsigned u; } v; v.f = f;
  unsigned r = (v.u + 0x7fffu + ((v.u >> 16) & 1u)) >> 16;
  return (unsigned short)r;
}
__device__ __forceinline__ float bf2f(unsigned short u) {
  union { float f; unsigned u; } v; v.u = ((unsigned)u) << 16;
  return v.f;
}
__device__ __forceinline__ void gld_lds16(const void* g, void* l) {
  __builtin_amdgcn_global_load_lds(
      (__attribute__((address_space(1))) void*)g,
      (__attribute__((address_space(3))) void*)l, 16, 0, 0);
}

// ---------- K1 (merged phase-1): LN stats + g(proto) + Wc ----------
// bid <  512 : k_stats   (b = bid>>4, ec = bid&15)
// bid <  832 : k_gproto  (mn = idx>>3, tc = idx&7)
// bid < 1024 : k_wc      (elem = idx*512 + tid)
__global__ void k_phase1(const float* __restrict__ x, float* __restrict__ ssum,
                         float* __restrict__ ssq, const float* __restrict__ proto,
                         float* __restrict__ g_p, const float* __restrict__ conv_w,
                         float* __restrict__ Wc) {
  int bid = blockIdx.x, tid = threadIdx.x;   // 512 threads
  if (bid < 512) {
    int b = bid >> 4, ec = bid & 15;
    int t = tid;
    float s = 0.f, q = 0.f;
    for (int i = 0; i < 16; ++i) {
      int e = ec * 16 + i;
      float2 v = *(const float2*)&x[(((size_t)b * En + e) * Tn + t) * 2];
      s += v.x + v.y; q += v.x * v.x + v.y * v.y;
    }
    atomicAdd(&ssum[b * Tn + t], s);
    atomicAdd(&ssq[b * Tn + t], q);
  } else if (bid < 832) {
    int idx = bid - 512;
    int mn = idx >> 3, tc = idx & 7;
    int c = tid;
    const float* p = proto + (size_t)mn * Tn * C2;
    float s = 0.f;
    for (int i = 0; i < 64; ++i) s += p[(size_t)(tc * 64 + i) * C2 + c];
    atomicAdd(&g_p[mn * 1536 + c], s);
    if (tc == 0) g_p[mn * 1536 + 1024 + c] = p[c];
    if (tc == 7) g_p[mn * 1536 + 512 + c] = p[(size_t)(Tn - 1) * C2 + c];
  } else {
    int idx = (bid - 832) * 512 + tid;
    if (idx >= 1536 * 64) return;
    int r = idx & 63, k = idx >> 6;
    float v;
    if (k < 512)       { const float* w = &conv_w[(r * 512 + k) * 3]; v = w[0] + w[1] + w[2]; }
    else if (k < 1024) v = -conv_w[(r * 512 + (k - 512)) * 3 + 0];
    else               v = -conv_w[(r * 512 + (k - 1024)) * 3 + 2];
    Wc[k * 64 + r] = v * (1.0f / Tn);
  }
}

// ---------- K2: permute + LN + bf16 hi/lo split into A[:,512:1024] + g(xn) ----------
__global__ void k_ln(const float* __restrict__ x, const float* __restrict__ ssum,
                     const float* __restrict__ ssq, const float* __restrict__ lng,
                     const float* __restrict__ lnb, unsigned short* __restrict__ Ah,
                     unsigned short* __restrict__ Al, float* __restrict__ g_xn) {
  __shared__ float lds[64 * 66];
  int t0 = blockIdx.x * 64, e0 = blockIdx.y * 32, b = blockIdx.z;
  int tq = threadIdx.x & 63, eq = threadIdx.x >> 6;
  // read (E-major) coalesced along t, transpose through LDS
  for (int i = 0; i < 8; ++i) {
    int e = e0 + eq * 8 + i;
    float2 v = *(const float2*)&x[(((size_t)b * En + e) * Tn + t0 + tq) * 2];
    int c0 = (eq * 8 + i) * 2;
    lds[tq * 66 + c0] = v.x; lds[tq * 66 + c0 + 1] = v.y;
  }
  __syncthreads();
  int c4 = threadIdx.x & 15, tw = threadIdx.x >> 4;
  int cg = e0 * 2 + c4 * 4;
  float gv4[4], bv4[4], psum[4] = {0.f, 0.f, 0.f, 0.f};
  for (int i = 0; i < 4; ++i) { gv4[i] = lng[cg + i]; bv4[i] = lnb[cg + i]; }
  for (int p = 0; p < 4; ++p) {
    int tl = p * 16 + tw;
    int t = t0 + tl;
    float mu = ssum[b * Tn + t] * (1.0f / C2);
    float var = ssq[b * Tn + t] * (1.0f / C2) - mu * mu;
    float rstd = rsqrtf(var + 1e-5f);
    ushort4 hh, ll;
    float xn[4];
    for (int i = 0; i < 4; ++i) {
      float xv = lds[tl * 66 + c4 * 4 + i];
      xn[i] = (xv - mu) * rstd * gv4[i] + bv4[i];
      psum[i] += xn[i];
    }
    hh.x = f2bf(xn[0]); hh.y = f2bf(xn[1]); hh.z = f2bf(xn[2]); hh.w = f2bf(xn[3]);
    ll.x = f2bf(xn[0] - bf2f(hh.x)); ll.y = f2bf(xn[1] - bf2f(hh.y));
    ll.z = f2bf(xn[2] - bf2f(hh.z)); ll.w = f2bf(xn[3] - bf2f(hh.w));
    size_t base = ((size_t)(b * Tn + t)) * KBIG + C2 + cg;
    *(ushort4*)&Ah[base] = hh;
    *(ushort4*)&Al[base] = ll;
    if (t == 0)      for (int i = 0; i < 4; ++i) g_xn[b * 1536 + 1024 + cg + i] = xn[i];
    if (t == Tn - 1) for (int i = 0; i < 4; ++i) g_xn[b * 1536 + 512 + cg + i] = xn[i];
  }
  __syncthreads();
  for (int i = 0; i < 4; ++i) lds[tw * 68 + c4 * 4 + i] = psum[i];
  __syncthreads();
  if (threadIdx.x < 64) {
    float s = 0.f;
    for (int r = 0; r < 16; ++r) s += lds[r * 68 + threadIdx.x];
    atomicAdd(&g_xn[b * 1536 + e0 * 2 + threadIdx.x], s);
  }
}

// ---------- K5: pooled features for xn (32 rows) + prototypes (40 rows) ----------
__global__ void k_pool(const float* __restrict__ g_xn, const float* __restrict__ g_p,
                       const float* __restrict__ Wc, const float* __restrict__ conv_b,
                       const float* __restrict__ pool_w, const float* __restrict__ pool_b,
                       float* __restrict__ x_q, float* __restrict__ pks) {
  __shared__ float sp[4 * 64 + 64];
  int rid = blockIdx.x;
  const float* g = (rid < 32) ? (g_xn + (size_t)rid * 1536) : (g_p + (size_t)(rid - 32) * 1536);
  float* out = (rid < 32) ? (x_q + (size_t)rid * 512) : (pks + (size_t)(rid - 32) * 512);
  int r = threadIdx.x & 63, kq = threadIdx.x >> 6;
  float partial = 0.f;
  for (int k = kq; k < 1536; k += 4) partial += g[k] * Wc[k * 64 + r];
  sp[kq * 64 + r] = partial;
  __syncthreads();
  if (threadIdx.x < 64)
    sp[256 + threadIdx.x] = sp[threadIdx.x] + sp[64 + threadIdx.x] + sp[128 + threadIdx.x] +
                            sp[192 + threadIdx.x] + conv_b[threadIdx.x];
  __syncthreads();
  for (int j = threadIdx.x; j < 512; j += 256) {
    float o = pool_b[j];
    for (int rr = 0; rr < 64; ++rr) o += sp[256 + rr] * pool_w[rr * 512 + j];
    out[j] = o;
  }
}

// ---------- generic small fp32 GEMM: C = A@B + bias*bscale ; up to 3 ops per launch ----------
__global__ void k_sgemm(const float* A0, int lda0, const float* B0, const float* bias0, float bs0, float* C0, int rows0, int K0,
                        const float* A1, int lda1, const float* B1, const float* bias1, float bs1, float* C1, int rows1, int K1,
                        const float* A2, int lda2, const float* B2, const float* bias2, float bs2, float* C2v, int rows2, int K2) {
  const float* A; int lda; const float* B; const float* bias; float bs; float* C; int rows; int K;
  if (blockIdx.z == 0)      { A = A0; lda = lda0; B = B0; bias = bias0; bs = bs0; C = C0; rows = rows0; K = K0; }
  else if (blockIdx.z == 1) { A = A1; lda = lda1; B = B1; bias = bias1; bs = bs1; C = C1; rows = rows1; K = K1; }
  else                      { A = A2; lda = lda2; B = B2; bias = bias2; bs = bs2; C = C2v; rows = rows2; K = K2; }
  if (!A) return;
  int r0 = blockIdx.x * 64;
  if (r0 >= rows) return;
  int c0 = blockIdx.y * 64;
  __shared__ float sA[64 * 17], sB[16 * 65];
  int tx = threadIdx.x & 15, ty = threadIdx.x >> 4;
  float acc[4][4] = {{0.f}};
  for (int kt = 0; kt < K; kt += 16) {
    for (int i = 0; i < 4; ++i) {
      int e = i * 256 + threadIdx.x;
      int rr = e >> 4, kk = e & 15;
      sA[rr * 17 + kk] = (r0 + rr < rows) ? A[(size_t)(r0 + rr) * lda + kt + kk] : 0.f;
      int kk2 = e >> 6, cc = e & 63;
      sB[kk2 * 65 + cc] = B[(size_t)(kt + kk2) * 512 + c0 + cc];
    }
    __syncthreads();
#pragma unroll
    for (int kk = 0; kk < 16; ++kk) {
      float av[4], bvv[4];
#pragma unroll
      for (int i = 0; i < 4; ++i) av[i] = sA[(ty * 4 + i) * 17 + kk];
#pragma unroll
      for (int j = 0; j < 4; ++j) bvv[j] = sB[kk * 65 + tx * 4 + j];
#pragma unroll
      for (int i = 0; i < 4; ++i)
#pragma unroll
        for (int j = 0; j < 4; ++j) acc[i][j] += av[i] * bvv[j];
    }
    __syncthreads();
  }
  for (int i = 0; i < 4; ++i) {
    int row = r0 + ty * 4 + i;
    if (row >= rows) break;
    for (int j = 0; j < 4; ++j) {
      int col = c0 + tx * 4 + j;
      float v = acc[i][j];
      if (bias) v += bias[col] * bs;
      C[(size_t)row * 512 + col] = v;
    }
  }
}

// ---------- K6: inner attention weights aw1 (B,M,N) ----------
// mask dtype is ambiguous (jnp bool): detect int32 {0,1} vs packed bytes.
__global__ void k_aw1(const float* __restrict__ q_prot, const float* __restrict__ keys_p,
                      const unsigned int* __restrict__ mask_w, float* __restrict__ aw1) {
  __shared__ float sc[40];
  __shared__ int isbyte;
  int b = blockIdx.x, tid = threadIdx.x;     // 64 threads
  if (tid == 0) {
    int ib = 0;
    for (int i = 0; i < 10; ++i) if (mask_w[i] > 1u) ib = 1;   // 40 bytes: safe for both dtypes
    isbyte = ib;
  }
  __syncthreads();
  if (tid < 40) {
    int mv = isbyte ? (int)((const unsigned char*)mask_w)[tid] : (int)mask_w[tid];
    const float4* qp = (const float4*)(q_prot + (size_t)b * 512);
    const float4* kp = (const float4*)(keys_p + (size_t)tid * 512);
    float d = 0.f;
    for (int k = 0; k < 128; ++k) {
      float4 a = qp[k], c = kp[k];
      d += a.x * c.x + a.y * c.y + a.z * c.z + a.w * c.w;
    }
    sc[tid] = mv ? d * SCALE_INV : -3.0e38f;
  }
  __syncthreads();
  if (tid < 8) {
    float mx = -3.0e38f;
    for (int n = 0; n < 5; ++n) mx = fmaxf(mx, sc[tid * 5 + n]);
    float e[5], s = 0.f;
    for (int n = 0; n < 5; ++n) { e[n] = __expf(sc[tid * 5 + n] - mx); s += e[n]; }
    for (int n = 0; n < 5; ++n) aw1[b * 40 + tid * 5 + n] = e[n] / s;
  }
}

// ---------- K7: y_ks rows via linear-pool identity ----------
__global__ void k_gy_pool(const float* __restrict__ aw1, const float* __restrict__ gvS,
                          const float* __restrict__ gvL, const float* __restrict__ gvF,
                          const float* __restrict__ Wc, const float* __restrict__ conv_b,
                          const float* __restrict__ pool_w, const float* __restrict__ pool_b,
                          float* __restrict__ y_ks) {
  __shared__ float g[1536];
  __shared__ float sp[4 * 64 + 64];
  int bm = blockIdx.x, m = bm & 7;
  float a[5];
  for (int n = 0; n < 5; ++n) a[n] = aw1[bm * 5 + n];
  for (int c = threadIdx.x; c < 512; c += 256) {
    float s0 = 0.f, s1 = 0.f, s2 = 0.f;
    for (int n = 0; n < 5; ++n) {
      size_t rw = (size_t)(m * 5 + n) * 512 + c;
      s0 += a[n] * gvS[rw]; s1 += a[n] * gvL[rw]; s2 += a[n] * gvF[rw];
    }
    g[c] = s0; g[512 + c] = s1; g[1024 + c] = s2;
  }
  __syncthreads();
  int r = threadIdx.x & 63, kq = threadIdx.x >> 6;
  float partial = 0.f;
  for (int k = kq; k < 1536; k += 4) partial += g[k] * Wc[k * 64 + r];
  sp[kq * 64 + r] = partial;
  __syncthreads();
  if (threadIdx.x < 64)
    sp[256 + threadIdx.x] = sp[threadIdx.x] + sp[64 + threadIdx.x] + sp[128 + threadIdx.x] +
                            sp[192 + threadIdx.x] + conv_b[threadIdx.x];
  __syncthreads();
  for (int j = threadIdx.x; j < 512; j += 256) {
    float o = pool_b[j];
    for (int rr = 0; rr < 64; ++rr) o += sp[256 + rr] * pool_w[rr * 512 + j];
    y_ks[(size_t)bm * 512 + j] = o;
  }
}

// ---------- K8: outer softmax aw2 (-> d_out tail) + combined weights wts ----------
__global__ void k_aw2(const float* __restrict__ qv, const float* __restrict__ kv,
                      const float* __restrict__ aw1, float* __restrict__ wts,
                      float* __restrict__ d_aw2) {
  __shared__ float s8[8];
  __shared__ float a2[8];
  int b = blockIdx.x;
  int m = threadIdx.x >> 6, lane = threadIdx.x & 63;   // 512 threads
  float partial = 0.f;
  for (int i = 0; i < 8; ++i) {
    int k = lane + i * 64;
    partial += qv[(size_t)b * 512 + k] * kv[(size_t)(b * 8 + m) * 512 + k];
  }
  for (int off = 32; off > 0; off >>= 1) partial += __shfl_down(partial, off, 64);
  if (lane == 0) s8[m] = partial;
  __syncthreads();
  if (threadIdx.x == 0) {
    float mx = -3.0e38f;
    for (int i = 0; i < 8; ++i) mx = fmaxf(mx, s8[i] * SCALE_INV);
    float s = 0.f;
    for (int i = 0; i < 8; ++i) { a2[i] = __expf(s8[i] * SCALE_INV - mx); s += a2[i]; }
    for (int i = 0; i < 8; ++i) { a2[i] /= s; d_aw2[b * 8 + i] = a2[i]; }
  }
  __syncthreads();
  if (threadIdx.x < 40) wts[b * 40 + threadIdx.x] = a2[threadIdx.x / 5] * aw1[b * 40 + threadIdx.x];
}

// ---------- K9: P = wts @ proto, split to bf16 hi/lo into A[:,0:512] ----------
__global__ void k_p(const float* __restrict__ proto, const float* __restrict__ wts,
                    unsigned short* __restrict__ Ah, unsigned short* __restrict__ Al) {
  __shared__ float sw[16 * 40];
  int chunk = blockIdx.x;    // 256 chunks of 1024 floats (2 t-rows)
  int bg = blockIdx.y;       // 2 groups of 16 b
  for (int i = threadIdx.x; i < 16 * 40; i += 256)
    sw[i] = wts[(bg * 16 + (i / 40)) * 40 + (i % 40)];
  __syncthreads();
  int x0 = chunk * 1024 + threadIdx.x * 4;
  f32x4 acc[16];
#pragma unroll
  for (int j = 0; j < 16; ++j) acc[j] = (f32x4){0.f, 0.f, 0.f, 0.f};
  for (int mn = 0; mn < 40; ++mn) {
    float4 pv = *(const float4*)&proto[(size_t)mn * Tn * C2 + x0];
#pragma unroll
    for (int j = 0; j < 16; ++j) {
      float w = sw[j * 40 + mn];
      acc[j].x += w * pv.x; acc[j].y += w * pv.y; acc[j].z += w * pv.z; acc[j].w += w * pv.w;
    }
  }
  int t = x0 >> 9, c = x0 & 511;
#pragma unroll
  for (int j = 0; j < 16; ++j) {
    int b = bg * 16 + j;
    size_t base = ((size_t)(b * Tn + t)) * KBIG + c;
    ushort4 hh, ll;
    hh.x = f2bf(acc[j].x); hh.y = f2bf(acc[j].y); hh.z = f2bf(acc[j].z); hh.w = f2bf(acc[j].w);
    ll.x = f2bf(acc[j].x - bf2f(hh.x)); ll.y = f2bf(acc[j].y - bf2f(hh.y));
    ll.z = f2bf(acc[j].z - bf2f(hh.z)); ll.w = f2bf(acc[j].w - bf2f(hh.w));
    *(ushort4*)&Ah[base] = hh;
    *(ushort4*)&Al[base] = ll;
  }
}

// ---------- K10: combined big-GEMM weight, transposed + split: Wt[n][k] ----------
__global__ void k_wbig(const float* __restrict__ W1, const float* __restrict__ wy,
                       unsigned short* __restrict__ Bh, unsigned short* __restrict__ Bl) {
  __shared__ float td[32 * 33];
  int n0 = blockIdx.x * 32, k0 = blockIdx.y * 32;
  for (int i = 0; i < 4; ++i) {
    int kk = i * 8 + (threadIdx.x >> 5);
    int nn = threadIdx.x & 31;
    int kg = k0 + kk;
    float v = (kg < 512) ? W1[(size_t)kg * 512 + n0 + nn] : wy[(size_t)(kg - 512) * 512 + n0 + nn];
    td[kk * 33 + nn] = v;
  }
  __syncthreads();
  for (int i = 0; i < 4; ++i) {
    int nn = i * 8 + (threadIdx.x >> 5);
    int kk = threadIdx.x & 31;
    float v = td[kk * 33 + nn];
    unsigned short h = f2bf(v);
    unsigned short l = f2bf(v - bf2f(h));
    size_t idx = (size_t)(n0 + nn) * KBIG + k0 + kk;
    Bh[idx] = h; Bl[idx] = l;
  }
}

// ---------- K11: big GEMM (16384x1024)@(1024x512) split-bf16 3-term MFMA ----------
// T3-minimum double-buffered pipeline: BK=32, 2x32KB LDS buffers.
// Per iter: STAGE(next tile) || ds_read+48 MFMA(cur) -> vmcnt(0)+barrier.
// 1-D grid of 512, XCD-bijective swizzle: XCD x owns 16 consecutive m-panels
// x 4 n-blocks -> A panel reuse stays within one XCD's L2.
__global__ __launch_bounds__(256, 2)
void k_gemm(const unsigned short* __restrict__ Ah, const unsigned short* __restrict__ Al,
            const unsigned short* __restrict__ Bh, const unsigned short* __restrict__ Bl,
            const float* __restrict__ bconst, float* __restrict__ out) {
  __shared__ __align__(16) char smem[65536];
  int tid = threadIdx.x;
  int wave = tid >> 6, lane = tid & 63;
  int wm = wave >> 1, wn = wave & 1;
  int L = blockIdx.x;
  int w = (L & 7) * 64 + (L >> 3);      // bijective on 0..511
  int m0 = (w >> 2) * 128, n0 = (w & 3) * 128;
  int r16 = lane & 15, kg = lane >> 4;
  // staging geometry per 1KB chunk: 16 rows x 4 slots of 16B; lane l -> row l>>2, slot l&3
  // source pre-swizzle: slot s holds global k-chunk s ^ ((row>>1)&3); ((row>>1)&3)=(l>>3)&3
  int srow = lane >> 2, csw = (lane & 3) ^ ((lane >> 3) & 3);

  f32x4 acc[4][4];
#pragma unroll
  for (int i = 0; i < 4; ++i)
#pragma unroll
    for (int j = 0; j < 4; ++j) acc[i][j] = (f32x4){0.f, 0.f, 0.f, 0.f};

  // STAGE one BK=32 K-tile into buffer buf (32KB: Ah|Al|Bh|Bl of 8KB each)
  auto STAGE = [&](int buf, int kt) {
    int k0 = kt * 32;
    char* base = smem + buf * 32768;
#pragma unroll
    for (int i = 0; i < 2; ++i) {
      int chunk = wave * 2 + i;            // 0..7
      int row = chunk * 16 + srow;         // 0..127
      size_t ga = (size_t)(m0 + row) * KBIG + k0 + csw * 8;
      size_t gb = (size_t)(n0 + row) * KBIG + k0 + csw * 8;
      int loff = chunk * 1024;
      gld_lds16(Ah + ga, base + loff);
      gld_lds16(Al + ga, base + 8192 + loff);
      gld_lds16(Bh + gb, base + 16384 + loff);
      gld_lds16(Bl + gb, base + 24576 + loff);
    }
  };

  STAGE(0, 0);
  __syncthreads();     // implies vmcnt(0) drain before first reads
  int cur = 0;
  for (int kt = 0; kt < 32; ++kt) {
    if (kt + 1 < 32) STAGE(cur ^ 1, kt + 1);   // prefetch flies under MFMA below
    char* cb = smem + cur * 32768;
    bf16x8 ah[4], al[4], bh[4], bl[4];
#pragma unroll
    for (int m = 0; m < 4; ++m) {
      int row = wm * 64 + m * 16 + r16;
      int off = row * 64 + ((kg ^ ((row >> 1) & 3)) << 4);
      ah[m] = *(const bf16x8*)(cb + off);
      al[m] = *(const bf16x8*)(cb + 8192 + off);
    }
#pragma unroll
    for (int n = 0; n < 4; ++n) {
      int row = wn * 64 + n * 16 + r16;
      int off = row * 64 + ((kg ^ ((row >> 1) & 3)) << 4);
      bh[n] = *(const bf16x8*)(cb + 16384 + off);
      bl[n] = *(const bf16x8*)(cb + 24576 + off);
    }
#pragma unroll
    for (int m = 0; m < 4; ++m)
#pragma unroll
      for (int n = 0; n < 4; ++n) {
        acc[m][n] = __builtin_amdgcn_mfma_f32_16x16x32_bf16(ah[m], bh[n], acc[m][n], 0, 0, 0);
        acc[m][n] = __builtin_amdgcn_mfma_f32_16x16x32_bf16(ah[m], bl[n], acc[m][n], 0, 0, 0);
        acc[m][n] = __builtin_amdgcn_mfma_f32_16x16x32_bf16(al[m], bh[n], acc[m][n], 0, 0, 0);
      }
    __syncthreads();   // drains vmcnt (next buf ready) + all waves done with cur
    cur ^= 1;
  }

  // epilogue: LDS transpose so final writes are contiguous in t
  float* sC = (float*)smem;   // 64 x 130 (stride 130: float2-aligned, 4-way banks)
  for (int pass = 0; pass < 2; ++pass) {
    if (wm == pass) {
#pragma unroll
      for (int m = 0; m < 4; ++m)
#pragma unroll
        for (int n = 0; n < 4; ++n)
#pragma unroll
          for (int r = 0; r < 4; ++r) {
            int trow = m * 16 + kg * 4 + r;
            int tcol = wn * 64 + n * 16 + r16;
            sC[trow * 130 + tcol] = acc[m][n][r];
          }
    }
    __syncthreads();
    {
      int trow = tid & 63, eg = tid >> 6;
      int grow = m0 + pass * 64 + trow;
      int b = grow >> 9, t = grow & 511;
      for (int i = 0; i < 16; ++i) {
        int ep = eg * 16 + i;
        int j0 = n0 + ep * 2;
        float2 vv;
        vv.x = sC[trow * 130 + ep * 2] + bconst[j0];
        vv.y = sC[trow * 130 + ep * 2 + 1] + bconst[j0 + 1];
        *(float2*)&out[(size_t)b * (En * Tn * 2) + (size_t)(j0 >> 1) * (Tn * 2) + t * 2] = vv;
      }
    }
    __syncthreads();
  }
}

// ---------- host ----------
extern "C" void kernel_launch(void* const* d_in, const int* in_sizes, int n_in,
                              void* d_out, int out_size, void* d_ws, size_t ws_size,
                              hipStream_t stream) {
  const float* x_ri  = (const float*)d_in[0];
  const float* proto = (const float*)d_in[1];
  const unsigned int* mask = (const unsigned int*)d_in[2];
  const float* conv_w = (const float*)d_in[3];
  const float* conv_b = (const float*)d_in[4];
  const float* pool_w = (const float*)d_in[5];
  const float* pool_b = (const float*)d_in[6];
  const float* ln_g = (const float*)d_in[7];
  const float* ln_b = (const float*)d_in[8];
  const float* wqp = (const float*)d_in[9];  const float* bqp = (const float*)d_in[10];
  const float* wkp = (const float*)d_in[11]; const float* bkp = (const float*)d_in[12];
  const float* wvp = (const float*)d_in[13]; const float* bvp = (const float*)d_in[14];
  const float* wq  = (const float*)d_in[15]; const float* bq  = (const float*)d_in[16];
  const float* wk  = (const float*)d_in[17]; const float* bk  = (const float*)d_in[18];
  const float* wv  = (const float*)d_in[19]; const float* bv  = (const float*)d_in[20];
  const float* wy  = (const float*)d_in[21]; const float* by  = (const float*)d_in[22];
  float* out = (float*)d_out;

  char* ws = (char*)d_ws;
  size_t off = 0;
  auto alloc = [&](size_t bytes) -> void* {
    void* p = ws + off;
    off = (off + bytes + 255) & ~(size_t)255;
    return p;
  };
  // zeroed region first (contiguous)
  float* ssum = (float*)alloc(16384 * 4);
  float* ssq  = (float*)alloc(16384 * 4);
  float* g_xn = (float*)alloc(32 * 1536 * 4);
  float* g_p  = (float*)alloc(40 * 1536 * 4);
  size_t zero_bytes = off;
  float* Wc    = (float*)alloc(1536 * 64 * 4);
  float* tmpW  = (float*)alloc(512 * 512 * 4);
  float* W1    = (float*)alloc(512 * 512 * 4);
  float* bvec  = (float*)alloc(512 * 4);
  float* bconst= (float*)alloc(512 * 4);
  float* x_q   = (float*)alloc(32 * 512 * 4);
  float* pks   = (float*)alloc(40 * 512 * 4);
  float* q_prot= (float*)alloc(32 * 512 * 4);
  float* keys_p= (float*)alloc(40 * 512 * 4);
  float* aw1   = (float*)alloc(1280 * 4);
  float* gvS   = (float*)alloc(40 * 512 * 4);
  float* gvL   = (float*)alloc(40 * 512 * 4);
  float* gvF   = (float*)alloc(40 * 512 * 4);
  float* y_ks  = (float*)alloc(256 * 512 * 4);
  float* qv    = (float*)alloc(32 * 512 * 4);
  float* kv    = (float*)alloc(256 * 512 * 4);
  float* wts   = (float*)alloc(1280 * 4);
  unsigned short* Bh = (unsigned short*)alloc((size_t)512 * 1024 * 2);
  unsigned short* Bl = (unsigned short*)alloc((size_t)512 * 1024 * 2);
  unsigned short* Ah = (unsigned short*)alloc((size_t)16384 * 1024 * 2);
  unsigned short* Al = (unsigned short*)alloc((size_t)16384 * 1024 * 2);

  hipMemsetAsync(d_ws, 0, zero_bytes, stream);

  k_phase1<<<dim3(1024), 512, 0, stream>>>(x_ri, ssum, ssq, proto, g_p, conv_w, Wc);
  k_ln<<<dim3(8, 8, 32), 256, 0, stream>>>(x_ri, ssum, ssq, ln_g, ln_b, Ah, Al, g_xn);
  // gv parts: S (bias T*bvp), last, first (bias bvp)
  k_sgemm<<<dim3(1, 8, 3), 256, 0, stream>>>(
      g_p + 0,    1536, wvp, bvp, 512.f, gvS, 40, 512,
      g_p + 512,  1536, wvp, bvp, 1.f,   gvL, 40, 512,
      g_p + 1024, 1536, wvp, bvp, 1.f,   gvF, 40, 512);
  // weight combine stage 1 + bvec
  k_sgemm<<<dim3(8, 8, 2), 256, 0, stream>>>(
      wvp, 512, wv, nullptr, 0.f, tmpW, 512, 512,
      bvp, 512, wv, bv,      1.f, bvec, 1,   512,
      nullptr, 0, nullptr, nullptr, 0.f, nullptr, 0, 0);
  // weight combine stage 2 + bconst
  k_sgemm<<<dim3(8, 8, 2), 256, 0, stream>>>(
      tmpW, 512, wy, nullptr, 0.f, W1,     512, 512,
      bvec, 512, wy, by,      1.f, bconst, 1,   512,
      nullptr, 0, nullptr, nullptr, 0.f, nullptr, 0, 0);
  k_wbig<<<dim3(16, 32), 256, 0, stream>>>(W1, wy, Bh, Bl);
  k_pool<<<dim3(72), 256, 0, stream>>>(g_xn, g_p, Wc, conv_b, pool_w, pool_b, x_q, pks);
  k_sgemm<<<dim3(1, 8, 2), 256, 0, stream>>>(
      x_q, 512, wqp, bqp, 1.f, q_prot, 32, 512,
      pks, 512, wkp, bkp, 1.f, keys_p, 40, 512,
      nullptr, 0, nullptr, nullptr, 0.f, nullptr, 0, 0);
  k_aw1<<<dim3(32), 64, 0, stream>>>(q_prot, keys_p, mask, aw1);
  k_gy_pool<<<dim3(256), 256, 0, stream>>>(aw1, gvS, gvL, gvF, Wc, conv_b, pool_w, pool_b, y_ks);
  k_sgemm<<<dim3(4, 8, 2), 256, 0, stream>>>(
      x_q,  512, wq, bq, 1.f, qv, 32,  512,
      y_ks, 512, wk, bk, 1.f, kv, 256, 512,
      nullptr, 0, nullptr, nullptr, 0.f, nullptr, 0, 0);
  k_aw2<<<dim3(32), 512, 0, stream>>>(qv, kv, aw1, wts, out + 8388608);
  k_p<<<dim3(256, 2), 256, 0, stream>>>(proto, wts, Ah, Al);
  k_gemm<<<dim3(512), 256, 0, stream>>>(Ah, Al, Bh, Bl, bconst, out);
}

// Round 9
// 714.370 us; speedup vs baseline: 1.1401x; 1.1401x over previous
//
#include <hip/hip_runtime.h>
#include <hip/hip_bf16.h>

// Sizes (fixed by the problem)
#define C2   512
#define Tn   512
#define Bn   32
#define En   256
#define Mn   8
#define Nn   5
#define MN   40
#define Rn   64
#define KBIG 1024
#define SCALE_INV (1.0f/22.62741699796952f)   // 1/sqrt(512)

typedef __attribute__((ext_vector_type(8))) __bf16 bf16x8;
typedef __attribute__((ext_vector_type(4))) float f32x4;

// ---------- helpers ----------
__device__ __forceinline__ unsigned short f2bf(float f) {
  union { float f; unsigned u; } v; v.f = f;
  unsigned r = (v.u + 0x7fffu + ((v.u >> 16) & 1u)) >> 16;
  return (unsigned short)r;
}
__device__ __forceinline__ float bf2f(unsigned short u) {
  union { float f; unsigned u; } v; v.u = ((unsigned)u) << 16;
  return v.f;
}
__device__ __forceinline__ void gld_lds16(const void* g, void* l) {
  __builtin_amdgcn_global_load_lds(
      (__attribute__((address_space(1))) void*)g,
      (__attribute__((address_space(3))) void*)l, 16, 0, 0);
}

// 8-chain ILP reduction over g[1536] x Wc[1536][64] -> 64 conv features.
// KQ = threads/64 (stride). 8 independent accumulators keep 8 loads in flight
// (fix for the 131us latency-serialized loop seen in round-6 rocprof).
template <int KQ>
__device__ __forceinline__ float wc_reduce(const float* __restrict__ g,
                                           const float* __restrict__ Wc,
                                           int r, int kq) {
  float p0 = 0.f, p1 = 0.f, p2 = 0.f, p3 = 0.f;
  float p4 = 0.f, p5 = 0.f, p6 = 0.f, p7 = 0.f;
  for (int k = kq; k < 1536; k += 8 * KQ) {
    p0 += g[k]          * Wc[(k)*64 + r];
    p1 += g[k + KQ]     * Wc[(k + KQ)*64 + r];
    p2 += g[k + 2*KQ]   * Wc[(k + 2*KQ)*64 + r];
    p3 += g[k + 3*KQ]   * Wc[(k + 3*KQ)*64 + r];
    p4 += g[k + 4*KQ]   * Wc[(k + 4*KQ)*64 + r];
    p5 += g[k + 5*KQ]   * Wc[(k + 5*KQ)*64 + r];
    p6 += g[k + 6*KQ]   * Wc[(k + 6*KQ)*64 + r];
    p7 += g[k + 7*KQ]   * Wc[(k + 7*KQ)*64 + r];
  }
  return ((p0 + p1) + (p2 + p3)) + ((p4 + p5) + (p6 + p7));
}

// ---------- K1 (merged phase-1): LN stats + g(proto) + Wc ----------
__global__ void k_phase1(const float* __restrict__ x, float* __restrict__ ssum,
                         float* __restrict__ ssq, const float* __restrict__ proto,
                         float* __restrict__ g_p, const float* __restrict__ conv_w,
                         float* __restrict__ Wc) {
  int bid = blockIdx.x, tid = threadIdx.x;   // 512 threads
  if (bid < 512) {
    int b = bid >> 4, ec = bid & 15;
    int t = tid;
    float s = 0.f, q = 0.f;
    for (int i = 0; i < 16; ++i) {
      int e = ec * 16 + i;
      float2 v = *(const float2*)&x[(((size_t)b * En + e) * Tn + t) * 2];
      s += v.x + v.y; q += v.x * v.x + v.y * v.y;
    }
    atomicAdd(&ssum[b * Tn + t], s);
    atomicAdd(&ssq[b * Tn + t], q);
  } else if (bid < 832) {
    int idx = bid - 512;
    int mn = idx >> 3, tc = idx & 7;
    int c = tid;
    const float* p = proto + (size_t)mn * Tn * C2;
    float s = 0.f;
    for (int i = 0; i < 64; ++i) s += p[(size_t)(tc * 64 + i) * C2 + c];
    atomicAdd(&g_p[mn * 1536 + c], s);
    if (tc == 0) g_p[mn * 1536 + 1024 + c] = p[c];
    if (tc == 7) g_p[mn * 1536 + 512 + c] = p[(size_t)(Tn - 1) * C2 + c];
  } else {
    int idx = (bid - 832) * 512 + tid;
    if (idx >= 1536 * 64) return;
    int r = idx & 63, k = idx >> 6;
    float v;
    if (k < 512)       { const float* w = &conv_w[(r * 512 + k) * 3]; v = w[0] + w[1] + w[2]; }
    else if (k < 1024) v = -conv_w[(r * 512 + (k - 512)) * 3 + 0];
    else               v = -conv_w[(r * 512 + (k - 1024)) * 3 + 2];
    Wc[k * 64 + r] = v * (1.0f / Tn);
  }
}

// ---------- K2: permute + LN + bf16 hi/lo split into A[:,512:1024] + g(xn) ----------
__global__ void k_ln(const float* __restrict__ x, const float* __restrict__ ssum,
                     const float* __restrict__ ssq, const float* __restrict__ lng,
                     const float* __restrict__ lnb, unsigned short* __restrict__ Ah,
                     unsigned short* __restrict__ Al, float* __restrict__ g_xn) {
  __shared__ float lds[64 * 66];
  int t0 = blockIdx.x * 64, e0 = blockIdx.y * 32, b = blockIdx.z;
  int tq = threadIdx.x & 63, eq = threadIdx.x >> 6;
  for (int i = 0; i < 8; ++i) {
    int e = e0 + eq * 8 + i;
    float2 v = *(const float2*)&x[(((size_t)b * En + e) * Tn + t0 + tq) * 2];
    int c0 = (eq * 8 + i) * 2;
    lds[tq * 66 + c0] = v.x; lds[tq * 66 + c0 + 1] = v.y;
  }
  __syncthreads();
  int c4 = threadIdx.x & 15, tw = threadIdx.x >> 4;
  int cg = e0 * 2 + c4 * 4;
  float gv4[4], bv4[4], psum[4] = {0.f, 0.f, 0.f, 0.f};
  for (int i = 0; i < 4; ++i) { gv4[i] = lng[cg + i]; bv4[i] = lnb[cg + i]; }
  for (int p = 0; p < 4; ++p) {
    int tl = p * 16 + tw;
    int t = t0 + tl;
    float mu = ssum[b * Tn + t] * (1.0f / C2);
    float var = ssq[b * Tn + t] * (1.0f / C2) - mu * mu;
    float rstd = rsqrtf(var + 1e-5f);
    ushort4 hh, ll;
    float xn[4];
    for (int i = 0; i < 4; ++i) {
      float xv = lds[tl * 66 + c4 * 4 + i];
      xn[i] = (xv - mu) * rstd * gv4[i] + bv4[i];
      psum[i] += xn[i];
    }
    hh.x = f2bf(xn[0]); hh.y = f2bf(xn[1]); hh.z = f2bf(xn[2]); hh.w = f2bf(xn[3]);
    ll.x = f2bf(xn[0] - bf2f(hh.x)); ll.y = f2bf(xn[1] - bf2f(hh.y));
    ll.z = f2bf(xn[2] - bf2f(hh.z)); ll.w = f2bf(xn[3] - bf2f(hh.w));
    size_t base = ((size_t)(b * Tn + t)) * KBIG + C2 + cg;
    *(ushort4*)&Ah[base] = hh;
    *(ushort4*)&Al[base] = ll;
    if (t == 0)      for (int i = 0; i < 4; ++i) g_xn[b * 1536 + 1024 + cg + i] = xn[i];
    if (t == Tn - 1) for (int i = 0; i < 4; ++i) g_xn[b * 1536 + 512 + cg + i] = xn[i];
  }
  __syncthreads();
  for (int i = 0; i < 4; ++i) lds[tw * 68 + c4 * 4 + i] = psum[i];
  __syncthreads();
  if (threadIdx.x < 64) {
    float s = 0.f;
    for (int r = 0; r < 16; ++r) s += lds[r * 68 + threadIdx.x];
    atomicAdd(&g_xn[b * 1536 + e0 * 2 + threadIdx.x], s);
  }
}

// ---------- K5: pooled features for xn (32 rows) + prototypes (40 rows) ----------
// 512 threads, 8-chain ILP reduce (was 131us latency-bound with 1 chain).
__global__ void k_pool(const float* __restrict__ g_xn, const float* __restrict__ g_p,
                       const float* __restrict__ Wc, const float* __restrict__ conv_b,
                       const float* __restrict__ pool_w, const float* __restrict__ pool_b,
                       float* __restrict__ x_q, float* __restrict__ pks) {
  __shared__ float sp[8 * 64 + 64];
  int rid = blockIdx.x;
  const float* g = (rid < 32) ? (g_xn + (size_t)rid * 1536) : (g_p + (size_t)(rid - 32) * 1536);
  float* out = (rid < 32) ? (x_q + (size_t)rid * 512) : (pks + (size_t)(rid - 32) * 512);
  int r = threadIdx.x & 63, kq = threadIdx.x >> 6;     // 512 threads: kq 0..7
  sp[kq * 64 + r] = wc_reduce<8>(g, Wc, r, kq);
  __syncthreads();
  if (threadIdx.x < 64) {
    float s = conv_b[threadIdx.x];
#pragma unroll
    for (int q = 0; q < 8; ++q) s += sp[q * 64 + threadIdx.x];
    sp[512 + threadIdx.x] = s;
  }
  __syncthreads();
  if (threadIdx.x < 256)
    for (int j = threadIdx.x; j < 512; j += 256) {
      float o = pool_b[j];
#pragma unroll
      for (int rr = 0; rr < 64; ++rr) o += sp[512 + rr] * pool_w[rr * 512 + j];
      out[j] = o;
    }
}

// ---------- generic small fp32 GEMM ----------
__global__ void k_sgemm(const float* A0, int lda0, const float* B0, const float* bias0, float bs0, float* C0, int rows0, int K0,
                        const float* A1, int lda1, const float* B1, const float* bias1, float bs1, float* C1, int rows1, int K1,
                        const float* A2, int lda2, const float* B2, const float* bias2, float bs2, float* C2v, int rows2, int K2) {
  const float* A; int lda; const float* B; const float* bias; float bs; float* C; int rows; int K;
  if (blockIdx.z == 0)      { A = A0; lda = lda0; B = B0; bias = bias0; bs = bs0; C = C0; rows = rows0; K = K0; }
  else if (blockIdx.z == 1) { A = A1; lda = lda1; B = B1; bias = bias1; bs = bs1; C = C1; rows = rows1; K = K1; }
  else                      { A = A2; lda = lda2; B = B2; bias = bias2; bs = bs2; C = C2v; rows = rows2; K = K2; }
  if (!A) return;
  int r0 = blockIdx.x * 64;
  if (r0 >= rows) return;
  int c0 = blockIdx.y * 64;
  __shared__ float sA[64 * 17], sB[16 * 65];
  int tx = threadIdx.x & 15, ty = threadIdx.x >> 4;
  float acc[4][4] = {{0.f}};
  for (int kt = 0; kt < K; kt += 16) {
    for (int i = 0; i < 4; ++i) {
      int e = i * 256 + threadIdx.x;
      int rr = e >> 4, kk = e & 15;
      sA[rr * 17 + kk] = (r0 + rr < rows) ? A[(size_t)(r0 + rr) * lda + kt + kk] : 0.f;
      int kk2 = e >> 6, cc = e & 63;
      sB[kk2 * 65 + cc] = B[(size_t)(kt + kk2) * 512 + c0 + cc];
    }
    __syncthreads();
#pragma unroll
    for (int kk = 0; kk < 16; ++kk) {
      float av[4], bvv[4];
#pragma unroll
      for (int i = 0; i < 4; ++i) av[i] = sA[(ty * 4 + i) * 17 + kk];
#pragma unroll
      for (int j = 0; j < 4; ++j) bvv[j] = sB[kk * 65 + tx * 4 + j];
#pragma unroll
      for (int i = 0; i < 4; ++i)
#pragma unroll
        for (int j = 0; j < 4; ++j) acc[i][j] += av[i] * bvv[j];
    }
    __syncthreads();
  }
  for (int i = 0; i < 4; ++i) {
    int row = r0 + ty * 4 + i;
    if (row >= rows) break;
    for (int j = 0; j < 4; ++j) {
      int col = c0 + tx * 4 + j;
      float v = acc[i][j];
      if (bias) v += bias[col] * bs;
      C[(size_t)row * 512 + col] = v;
    }
  }
}

// ---------- K6: inner attention weights aw1 (B,M,N) ----------
__global__ void k_aw1(const float* __restrict__ q_prot, const float* __restrict__ keys_p,
                      const unsigned int* __restrict__ mask_w, float* __restrict__ aw1) {
  __shared__ float sc[40];
  __shared__ int isbyte;
  int b = blockIdx.x, tid = threadIdx.x;     // 64 threads
  if (tid == 0) {
    int ib = 0;
    for (int i = 0; i < 10; ++i) if (mask_w[i] > 1u) ib = 1;   // 40 bytes: safe for both dtypes
    isbyte = ib;
  }
  __syncthreads();
  if (tid < 40) {
    int mv = isbyte ? (int)((const unsigned char*)mask_w)[tid] : (int)mask_w[tid];
    const float4* qp = (const float4*)(q_prot + (size_t)b * 512);
    const float4* kp = (const float4*)(keys_p + (size_t)tid * 512);
    float d = 0.f;
    for (int k = 0; k < 128; ++k) {
      float4 a = qp[k], c = kp[k];
      d += a.x * c.x + a.y * c.y + a.z * c.z + a.w * c.w;
    }
    sc[tid] = mv ? d * SCALE_INV : -3.0e38f;
  }
  __syncthreads();
  if (tid < 8) {
    float mx = -3.0e38f;
    for (int n = 0; n < 5; ++n) mx = fmaxf(mx, sc[tid * 5 + n]);
    float e[5], s = 0.f;
    for (int n = 0; n < 5; ++n) { e[n] = __expf(sc[tid * 5 + n] - mx); s += e[n]; }
    for (int n = 0; n < 5; ++n) aw1[b * 40 + tid * 5 + n] = e[n] / s;
  }
}

// ---------- K7: y_ks rows via linear-pool identity (8-chain ILP reduce) ----------
__global__ void k_gy_pool(const float* __restrict__ aw1, const float* __restrict__ gvS,
                          const float* __restrict__ gvL, const float* __restrict__ gvF,
                          const float* __restrict__ Wc, const float* __restrict__ conv_b,
                          const float* __restrict__ pool_w, const float* __restrict__ pool_b,
                          float* __restrict__ y_ks) {
  __shared__ float g[1536];
  __shared__ float sp[4 * 64 + 64];
  int bm = blockIdx.x, m = bm & 7;
  float a[5];
  for (int n = 0; n < 5; ++n) a[n] = aw1[bm * 5 + n];
  for (int c = threadIdx.x; c < 512; c += 256) {
    float s0 = 0.f, s1 = 0.f, s2 = 0.f;
#pragma unroll
    for (int n = 0; n < 5; ++n) {
      size_t rw = (size_t)(m * 5 + n) * 512 + c;
      s0 += a[n] * gvS[rw]; s1 += a[n] * gvL[rw]; s2 += a[n] * gvF[rw];
    }
    g[c] = s0; g[512 + c] = s1; g[1024 + c] = s2;
  }
  __syncthreads();
  int r = threadIdx.x & 63, kq = threadIdx.x >> 6;   // 256 threads: kq 0..3
  sp[kq * 64 + r] = wc_reduce<4>(g, Wc, r, kq);
  __syncthreads();
  if (threadIdx.x < 64)
    sp[256 + threadIdx.x] = sp[threadIdx.x] + sp[64 + threadIdx.x] + sp[128 + threadIdx.x] +
                            sp[192 + threadIdx.x] + conv_b[threadIdx.x];
  __syncthreads();
  for (int j = threadIdx.x; j < 512; j += 256) {
    float o = pool_b[j];
#pragma unroll
    for (int rr = 0; rr < 64; ++rr) o += sp[256 + rr] * pool_w[rr * 512 + j];
    y_ks[(size_t)bm * 512 + j] = o;
  }
}

// ---------- K8: outer softmax aw2 (-> d_out tail) + combined weights wts ----------
__global__ void k_aw2(const float* __restrict__ qv, const float* __restrict__ kv,
                      const float* __restrict__ aw1, float* __restrict__ wts,
                      float* __restrict__ d_aw2) {
  __shared__ float s8[8];
  __shared__ float a2[8];
  int b = blockIdx.x;
  int m = threadIdx.x >> 6, lane = threadIdx.x & 63;   // 512 threads
  float partial = 0.f;
  for (int i = 0; i < 8; ++i) {
    int k = lane + i * 64;
    partial += qv[(size_t)b * 512 + k] * kv[(size_t)(b * 8 + m) * 512 + k];
  }
  for (int off = 32; off > 0; off >>= 1) partial += __shfl_down(partial, off, 64);
  if (lane == 0) s8[m] = partial;
  __syncthreads();
  if (threadIdx.x == 0) {
    float mx = -3.0e38f;
    for (int i = 0; i < 8; ++i) mx = fmaxf(mx, s8[i] * SCALE_INV);
    float s = 0.f;
    for (int i = 0; i < 8; ++i) { a2[i] = __expf(s8[i] * SCALE_INV - mx); s += a2[i]; }
    for (int i = 0; i < 8; ++i) { a2[i] /= s; d_aw2[b * 8 + i] = a2[i]; }
  }
  __syncthreads();
  if (threadIdx.x < 40) wts[b * 40 + threadIdx.x] = a2[threadIdx.x / 5] * aw1[b * 40 + threadIdx.x];
}

// ---------- K9: P = wts @ proto, split to bf16 hi/lo into A[:,0:512] ----------
__global__ void k_p(const float* __restrict__ proto, const float* __restrict__ wts,
                    unsigned short* __restrict__ Ah, unsigned short* __restrict__ Al) {
  __shared__ float sw[16 * 40];
  int chunk = blockIdx.x;    // 256 chunks of 1024 floats (2 t-rows)
  int bg = blockIdx.y;       // 2 groups of 16 b
  for (int i = threadIdx.x; i < 16 * 40; i += 256)
    sw[i] = wts[(bg * 16 + (i / 40)) * 40 + (i % 40)];
  __syncthreads();
  int x0 = chunk * 1024 + threadIdx.x * 4;
  f32x4 acc[16];
#pragma unroll
  for (int j = 0; j < 16; ++j) acc[j] = (f32x4){0.f, 0.f, 0.f, 0.f};
  for (int mn = 0; mn < 40; ++mn) {
    float4 pv = *(const float4*)&proto[(size_t)mn * Tn * C2 + x0];
#pragma unroll
    for (int j = 0; j < 16; ++j) {
      float w = sw[j * 40 + mn];
      acc[j].x += w * pv.x; acc[j].y += w * pv.y; acc[j].z += w * pv.z; acc[j].w += w * pv.w;
    }
  }
  int t = x0 >> 9, c = x0 & 511;
#pragma unroll
  for (int j = 0; j < 16; ++j) {
    int b = bg * 16 + j;
    size_t base = ((size_t)(b * Tn + t)) * KBIG + c;
    ushort4 hh, ll;
    hh.x = f2bf(acc[j].x); hh.y = f2bf(acc[j].y); hh.z = f2bf(acc[j].z); hh.w = f2bf(acc[j].w);
    ll.x = f2bf(acc[j].x - bf2f(hh.x)); ll.y = f2bf(acc[j].y - bf2f(hh.y));
    ll.z = f2bf(acc[j].z - bf2f(hh.z)); ll.w = f2bf(acc[j].w - bf2f(hh.w));
    *(ushort4*)&Ah[base] = hh;
    *(ushort4*)&Al[base] = ll;
  }
}

// ---------- K10: combined big-GEMM weight, transposed + split: Wt[n][k] ----------
__global__ void k_wbig(const float* __restrict__ W1, const float* __restrict__ wy,
                       unsigned short* __restrict__ Bh, unsigned short* __restrict__ Bl) {
  __shared__ float td[32 * 33];
  int n0 = blockIdx.x * 32, k0 = blockIdx.y * 32;
  for (int i = 0; i < 4; ++i) {
    int kk = i * 8 + (threadIdx.x >> 5);
    int nn = threadIdx.x & 31;
    int kg = k0 + kk;
    float v = (kg < 512) ? W1[(size_t)kg * 512 + n0 + nn] : wy[(size_t)(kg - 512) * 512 + n0 + nn];
    td[kk * 33 + nn] = v;
  }
  __syncthreads();
  for (int i = 0; i < 4; ++i) {
    int nn = i * 8 + (threadIdx.x >> 5);
    int kk = threadIdx.x & 31;
    float v = td[kk * 33 + nn];
    unsigned short h = f2bf(v);
    unsigned short l = f2bf(v - bf2f(h));
    size_t idx = (size_t)(n0 + nn) * KBIG + k0 + kk;
    Bh[idx] = h; Bl[idx] = l;
  }
}

// ---------- K11: big GEMM (16384x1024)@(1024x512) split-bf16 3-term MFMA ----------
__global__ __launch_bounds__(256, 2)
void k_gemm(const unsigned short* __restrict__ Ah, const unsigned short* __restrict__ Al,
            const unsigned short* __restrict__ Bh, const unsigned short* __restrict__ Bl,
            const float* __restrict__ bconst, float* __restrict__ out) {
  __shared__ __align__(16) char smem[65536];
  int tid = threadIdx.x;
  int wave = tid >> 6, lane = tid & 63;
  int wm = wave >> 1, wn = wave & 1;
  int L = blockIdx.x;
  int w = (L & 7) * 64 + (L >> 3);      // bijective on 0..511
  int m0 = (w >> 2) * 128, n0 = (w & 3) * 128;
  int r16 = lane & 15, kg = lane >> 4;
  int srow = lane >> 2, csw = (lane & 3) ^ ((lane >> 3) & 3);

  f32x4 acc[4][4];
#pragma unroll
  for (int i = 0; i < 4; ++i)
#pragma unroll
    for (int j = 0; j < 4; ++j) acc[i][j] = (f32x4){0.f, 0.f, 0.f, 0.f};

  auto STAGE = [&](int buf, int kt) {
    int k0 = kt * 32;
    char* base = smem + buf * 32768;
#pragma unroll
    for (int i = 0; i < 2; ++i) {
      int chunk = wave * 2 + i;            // 0..7
      int row = chunk * 16 + srow;         // 0..127
      size_t ga = (size_t)(m0 + row) * KBIG + k0 + csw * 8;
      size_t gb = (size_t)(n0 + row) * KBIG + k0 + csw * 8;
      int loff = chunk * 1024;
      gld_lds16(Ah + ga, base + loff);
      gld_lds16(Al + ga, base + 8192 + loff);
      gld_lds16(Bh + gb, base + 16384 + loff);
      gld_lds16(Bl + gb, base + 24576 + loff);
    }
  };

  STAGE(0, 0);
  __syncthreads();
  int cur = 0;
  for (int kt = 0; kt < 32; ++kt) {
    if (kt + 1 < 32) STAGE(cur ^ 1, kt + 1);
    char* cb = smem + cur * 32768;
    bf16x8 ah[4], al[4], bh[4], bl[4];
#pragma unroll
    for (int m = 0; m < 4; ++m) {
      int row = wm * 64 + m * 16 + r16;
      int off = row * 64 + ((kg ^ ((row >> 1) & 3)) << 4);
      ah[m] = *(const bf16x8*)(cb + off);
      al[m] = *(const bf16x8*)(cb + 8192 + off);
    }
#pragma unroll
    for (int n = 0; n < 4; ++n) {
      int row = wn * 64 + n * 16 + r16;
      int off = row * 64 + ((kg ^ ((row >> 1) & 3)) << 4);
      bh[n] = *(const bf16x8*)(cb + 16384 + off);
      bl[n] = *(const bf16x8*)(cb + 24576 + off);
    }
#pragma unroll
    for (int m = 0; m < 4; ++m)
#pragma unroll
      for (int n = 0; n < 4; ++n) {
        acc[m][n] = __builtin_amdgcn_mfma_f32_16x16x32_bf16(ah[m], bh[n], acc[m][n], 0, 0, 0);
        acc[m][n] = __builtin_amdgcn_mfma_f32_16x16x32_bf16(ah[m], bl[n], acc[m][n], 0, 0, 0);
        acc[m][n] = __builtin_amdgcn_mfma_f32_16x16x32_bf16(al[m], bh[n], acc[m][n], 0, 0, 0);
      }
    __syncthreads();
    cur ^= 1;
  }

  float* sC = (float*)smem;   // 64 x 130
  for (int pass = 0; pass < 2; ++pass) {
    if (wm == pass) {
#pragma unroll
      for (int m = 0; m < 4; ++m)
#pragma unroll
        for (int n = 0; n < 4; ++n)
#pragma unroll
          for (int r = 0; r < 4; ++r) {
            int trow = m * 16 + kg * 4 + r;
            int tcol = wn * 64 + n * 16 + r16;
            sC[trow * 130 + tcol] = acc[m][n][r];
          }
    }
    __syncthreads();
    {
      int trow = tid & 63, eg = tid >> 6;
      int grow = m0 + pass * 64 + trow;
      int b = grow >> 9, t = grow & 511;
      for (int i = 0; i < 16; ++i) {
        int ep = eg * 16 + i;
        int j0 = n0 + ep * 2;
        float2 vv;
        vv.x = sC[trow * 130 + ep * 2] + bconst[j0];
        vv.y = sC[trow * 130 + ep * 2 + 1] + bconst[j0 + 1];
        *(float2*)&out[(size_t)b * (En * Tn * 2) + (size_t)(j0 >> 1) * (Tn * 2) + t * 2] = vv;
      }
    }
    __syncthreads();
  }
}

// ---------- host ----------
extern "C" void kernel_launch(void* const* d_in, const int* in_sizes, int n_in,
                              void* d_out, int out_size, void* d_ws, size_t ws_size,
                              hipStream_t stream) {
  const float* x_ri  = (const float*)d_in[0];
  const float* proto = (const float*)d_in[1];
  const unsigned int* mask = (const unsigned int*)d_in[2];
  const float* conv_w = (const float*)d_in[3];
  const float* conv_b = (const float*)d_in[4];
  const float* pool_w = (const float*)d_in[5];
  const float* pool_b = (const float*)d_in[6];
  const float* ln_g = (const float*)d_in[7];
  const float* ln_b = (const float*)d_in[8];
  const float* wqp = (const float*)d_in[9];  const float* bqp = (const float*)d_in[10];
  const float* wkp = (const float*)d_in[11]; const float* bkp = (const float*)d_in[12];
  const float* wvp = (const float*)d_in[13]; const float* bvp = (const float*)d_in[14];
  const float* wq  = (const float*)d_in[15]; const float* bq  = (const float*)d_in[16];
  const float* wk  = (const float*)d_in[17]; const float* bk  = (const float*)d_in[18];
  const float* wv  = (const float*)d_in[19]; const float* bv  = (const float*)d_in[20];
  const float* wy  = (const float*)d_in[21]; const float* by  = (const float*)d_in[22];
  float* out = (float*)d_out;

  char* ws = (char*)d_ws;
  size_t off = 0;
  auto alloc = [&](size_t bytes) -> void* {
    void* p = ws + off;
    off = (off + bytes + 255) & ~(size_t)255;
    return p;
  };
  float* ssum = (float*)alloc(16384 * 4);
  float* ssq  = (float*)alloc(16384 * 4);
  float* g_xn = (float*)alloc(32 * 1536 * 4);
  float* g_p  = (float*)alloc(40 * 1536 * 4);
  size_t zero_bytes = off;
  float* Wc    = (float*)alloc(1536 * 64 * 4);
  float* tmpW  = (float*)alloc(512 * 512 * 4);
  float* W1    = (float*)alloc(512 * 512 * 4);
  float* bvec  = (float*)alloc(512 * 4);
  float* bconst= (float*)alloc(512 * 4);
  float* x_q   = (float*)alloc(32 * 512 * 4);
  float* pks   = (float*)alloc(40 * 512 * 4);
  float* q_prot= (float*)alloc(32 * 512 * 4);
  float* keys_p= (float*)alloc(40 * 512 * 4);
  float* aw1   = (float*)alloc(1280 * 4);
  float* gvS   = (float*)alloc(40 * 512 * 4);
  float* gvL   = (float*)alloc(40 * 512 * 4);
  float* gvF   = (float*)alloc(40 * 512 * 4);
  float* y_ks  = (float*)alloc(256 * 512 * 4);
  float* qv    = (float*)alloc(32 * 512 * 4);
  float* kv    = (float*)alloc(256 * 512 * 4);
  float* wts   = (float*)alloc(1280 * 4);
  unsigned short* Bh = (unsigned short*)alloc((size_t)512 * 1024 * 2);
  unsigned short* Bl = (unsigned short*)alloc((size_t)512 * 1024 * 2);
  unsigned short* Ah = (unsigned short*)alloc((size_t)16384 * 1024 * 2);
  unsigned short* Al = (unsigned short*)alloc((size_t)16384 * 1024 * 2);

  hipMemsetAsync(d_ws, 0, zero_bytes, stream);

  k_phase1<<<dim3(1024), 512, 0, stream>>>(x_ri, ssum, ssq, proto, g_p, conv_w, Wc);
  k_ln<<<dim3(8, 8, 32), 256, 0, stream>>>(x_ri, ssum, ssq, ln_g, ln_b, Ah, Al, g_xn);
  k_sgemm<<<dim3(1, 8, 3), 256, 0, stream>>>(
      g_p + 0,    1536, wvp, bvp, 512.f, gvS, 40, 512,
      g_p + 512,  1536, wvp, bvp, 1.f,   gvL, 40, 512,
      g_p + 1024, 1536, wvp, bvp, 1.f,   gvF, 40, 512);
  k_sgemm<<<dim3(8, 8, 2), 256, 0, stream>>>(
      wvp, 512, wv, nullptr, 0.f, tmpW, 512, 512,
      bvp, 512, wv, bv,      1.f, bvec, 1,   512,
      nullptr, 0, nullptr, nullptr, 0.f, nullptr, 0, 0);
  k_sgemm<<<dim3(8, 8, 2), 256, 0, stream>>>(
      tmpW, 512, wy, nullptr, 0.f, W1,     512, 512,
      bvec, 512, wy, by,      1.f, bconst, 1,   512,
      nullptr, 0, nullptr, nullptr, 0.f, nullptr, 0, 0);
  k_wbig<<<dim3(16, 32), 256, 0, stream>>>(W1, wy, Bh, Bl);
  k_pool<<<dim3(72), 512, 0, stream>>>(g_xn, g_p, Wc, conv_b, pool_w, pool_b, x_q, pks);
  k_sgemm<<<dim3(1, 8, 2), 256, 0, stream>>>(
      x_q, 512, wqp, bqp, 1.f, q_prot, 32, 512,
      pks, 512, wkp, bkp, 1.f, keys_p, 40, 512,
      nullptr, 0, nullptr, nullptr, 0.f, nullptr, 0, 0);
  k_aw1<<<dim3(32), 64, 0, stream>>>(q_prot, keys_p, mask, aw1);
  k_gy_pool<<<dim3(256), 256, 0, stream>>>(aw1, gvS, gvL, gvF, Wc, conv_b, pool_w, pool_b, y_ks);
  k_sgemm<<<dim3(4, 8, 2), 256, 0, stream>>>(
      x_q,  512, wq, bq, 1.f, qv, 32,  512,
      y_ks, 512, wk, bk, 1.f, kv, 256, 512,
      nullptr, 0, nullptr, nullptr, 0.f, nullptr, 0, 0);
  k_aw2<<<dim3(32), 512, 0, stream>>>(qv, kv, aw1, wts, out + 8388608);
  k_p<<<dim3(256, 2), 256, 0, stream>>>(proto, wts, Ah, Al);
  k_gemm<<<dim3(512), 256, 0, stream>>>(Ah, Al, Bh, Bl, bconst, out);
}